// Round 8
// baseline (360.691 us; speedup 1.0000x reference)
//
#include <hip/hip_runtime.h>
#include <hip/hip_bf16.h>
#include <cstdint>

// Problem constants: N=4096 tokens, D=1024, H=2048, E=8, TOP_K=2
#define N_TOK 4096
#define DIM   1024
#define HID   2048
#define NE    8

typedef __bf16 bf16x8 __attribute__((ext_vector_type(8)));
typedef __bf16 bf16x4 __attribute__((ext_vector_type(4)));
typedef float  f32x4  __attribute__((ext_vector_type(4)));

// Async global->LDS DMA, 16B/lane. LDS dest = wave-uniform base + lane*16.
__device__ __forceinline__ void gload16(const void* g, void* l) {
    __builtin_amdgcn_global_load_lds(
        (const __attribute__((address_space(1))) void*)g,
        (__attribute__((address_space(3))) void*)l, 16, 0, 0);
}

// ---------------------------------------------------------------------------
// Both weight transposes in one launch. lin<16384: W1 [D][H]->[H][D];
// else W2 [H][D]->[D][H]. 32x32 tiles via LDS.
// ---------------------------------------------------------------------------
__global__ void transpose_cvt_all(const float* __restrict__ W1, const float* __restrict__ W2,
                                  __bf16* __restrict__ w1t, __bf16* __restrict__ w2t) {
    int lin = blockIdx.x;
    const float* src; __bf16* dst; int R, C, rx, cy;
    if (lin < 16384) {
        const int e = lin >> 11, rem = lin & 2047;
        rx = rem >> 6; cy = rem & 63;           // R/32=32, C/32=64
        R = DIM; C = HID;
        src = W1 + (size_t)e * DIM * HID; dst = w1t + (size_t)e * DIM * HID;
    } else {
        lin -= 16384;
        const int e = lin >> 11, rem = lin & 2047;
        rx = rem >> 5; cy = rem & 31;           // R/32=64, C/32=32
        R = HID; C = DIM;
        src = W2 + (size_t)e * DIM * HID; dst = w2t + (size_t)e * DIM * HID;
    }
    __shared__ float t[32][33];
    const int r0 = rx * 32, c0 = cy * 32;
    const int tr = threadIdx.x >> 3;
    const int tc = (threadIdx.x & 7) * 4;
    float4 v = *(const float4*)&src[(size_t)(r0 + tr) * C + c0 + tc];
    t[tr][tc + 0] = v.x; t[tr][tc + 1] = v.y; t[tr][tc + 2] = v.z; t[tr][tc + 3] = v.w;
    __syncthreads();
    bf16x4 o;
    o[0] = (__bf16)t[tc + 0][tr];
    o[1] = (__bf16)t[tc + 1][tr];
    o[2] = (__bf16)t[tc + 2][tr];
    o[3] = (__bf16)t[tc + 3][tr];
    *(bf16x4*)&dst[(size_t)(c0 + tr) * R + r0 + tc] = o;
}

// ---------------------------------------------------------------------------
// Gating + x->bf16 conversion fused. One wave per token. No atomics.
// ---------------------------------------------------------------------------
__global__ void gate_kernel(const float* __restrict__ x, const float* __restrict__ gW,
                            const float* __restrict__ gb, int* __restrict__ top_idx,
                            float* __restrict__ top_gate, __bf16* __restrict__ xb) {
    const int tokn = blockIdx.x * 4 + (threadIdx.x >> 6);
    const int lane = threadIdx.x & 63;
    const float4* xr = (const float4*)(x + (size_t)tokn * DIM);
    __bf16* xbr = xb + (size_t)tokn * DIM;
    float acc[NE] = {};
#pragma unroll
    for (int i = 0; i < 4; i++) {
        const int v4 = i * 64 + lane;            // float4 index 0..255
        const float4 xv = xr[v4];
        bf16x4 xc = { (__bf16)xv.x, (__bf16)xv.y, (__bf16)xv.z, (__bf16)xv.w };
        *(bf16x4*)&xbr[v4 * 4] = xc;
        const float* wb = &gW[v4 * 4 * NE];      // 4 rows x 8 experts
        const float xs[4] = { xv.x, xv.y, xv.z, xv.w };
#pragma unroll
        for (int j = 0; j < 4; j++) {
            const float4 wa = *(const float4*)&wb[j * NE];
            const float4 wc = *(const float4*)&wb[j * NE + 4];
            acc[0] += xs[j] * wa.x; acc[1] += xs[j] * wa.y;
            acc[2] += xs[j] * wa.z; acc[3] += xs[j] * wa.w;
            acc[4] += xs[j] * wc.x; acc[5] += xs[j] * wc.y;
            acc[6] += xs[j] * wc.z; acc[7] += xs[j] * wc.w;
        }
    }
#pragma unroll
    for (int e = 0; e < NE; e++)
#pragma unroll
        for (int s = 32; s > 0; s >>= 1)
            acc[e] += __shfl_down(acc[e], s, 64);
    if (lane == 0) {
        float lg[NE], p[NE];
        float mx = -1e30f;
#pragma unroll
        for (int e = 0; e < NE; e++) { lg[e] = acc[e] + gb[e]; mx = fmaxf(mx, lg[e]); }
        float s = 0.f;
#pragma unroll
        for (int e = 0; e < NE; e++) { p[e] = __expf(lg[e] - mx); s += p[e]; }
        const float inv = 1.f / s;
#pragma unroll
        for (int e = 0; e < NE; e++) p[e] *= inv;
        int i0 = 0; float p0 = p[0];
#pragma unroll
        for (int e = 1; e < NE; e++) if (p[e] > p0) { p0 = p[e]; i0 = e; }
        int i1 = -1; float p1 = -1.f;
#pragma unroll
        for (int e = 0; e < NE; e++) if (e != i0 && p[e] > p1) { p1 = p[e]; i1 = e; }
        top_idx[tokn * 2] = i0;  top_idx[tokn * 2 + 1] = i1;
        top_gate[tokn * 2] = p0; top_gate[tokn * 2 + 1] = p1;
    }
}

// LDS histogram -> 8 global atomics per block (16 blocks => 128 total).
__global__ void count_kernel(const int* __restrict__ top_idx, int* __restrict__ cnt) {
    __shared__ int hist[NE];
    if (threadIdx.x < NE) hist[threadIdx.x] = 0;
    __syncthreads();
    const int n = blockIdx.x * 256 + threadIdx.x;
    atomicAdd(&hist[top_idx[n * 2]], 1);
    atomicAdd(&hist[top_idx[n * 2 + 1]], 1);
    __syncthreads();
    if (threadIdx.x < NE) atomicAdd(&cnt[threadIdx.x], hist[threadIdx.x]);
}

// Row assignment: inline 8-wide prefix scan + LDS ranks + 8 global atomics/block.
__global__ void build_kernel(const int* __restrict__ top_idx, const int* __restrict__ cnt,
                             int* __restrict__ run, int* __restrict__ row_token,
                             int* __restrict__ tok_row) {
    __shared__ int soffs[NE];
    __shared__ int lrun[NE];
    __shared__ int base[NE];
    if (threadIdx.x == 0) {
        int s = 0;
        for (int e = 0; e < NE; e++) { soffs[e] = s; s += cnt[e]; }
    }
    if (threadIdx.x < NE) lrun[threadIdx.x] = 0;
    __syncthreads();
    const int n = blockIdx.x * 256 + threadIdx.x;
    const int e0 = top_idx[n * 2], e1 = top_idx[n * 2 + 1];
    const int p0 = atomicAdd(&lrun[e0], 1);
    const int p1 = atomicAdd(&lrun[e1], 1);
    __syncthreads();
    if (threadIdx.x < NE) base[threadIdx.x] = atomicAdd(&run[threadIdx.x], lrun[threadIdx.x]);
    __syncthreads();
    const int r0 = soffs[e0] + base[e0] + p0;
    const int r1 = soffs[e1] + base[e1] + p1;
    row_token[r0] = n; tok_row[n * 2] = r0;
    row_token[r1] = n; tok_row[n * 2 + 1] = r1;
}

// ---------------------------------------------------------------------------
// Grouped GEMM1: h[r] = relu(x[tok(r)] @ W1t[e] + b1[e]), bf16 out.
// 128x128 tile, BK=64, DOUBLE-BUFFERED LDS, ONE barrier/iter:
//   barrier (drains DMA(k), issued a full iter earlier -> latency hidden);
//   issue DMA(k+1) into other buffer; compute(k).
// XOR-swizzled LDS (R5-verified: row=128B, chunk q of row r at slot q^(r&7)).
// XCD-aware packed grid: lin = e + 8*t; n0t = t&15 fast, mt = t>>4 slow.
// ---------------------------------------------------------------------------
__global__ __launch_bounds__(256, 2) void gemm1_kernel(
    const __bf16* __restrict__ xb, const __bf16* __restrict__ w1t,
    const float* __restrict__ b1, const int* __restrict__ cnt,
    const int* __restrict__ row_token, __bf16* __restrict__ h) {
    const int lin = blockIdx.x;
    const int e   = lin & 7;
    const int t   = lin >> 3;
    const int n0  = (t & 15) * 128;
    const int mt  = t >> 4;
    int off_e = 0;
    for (int i = 0; i < e; i++) off_e += cnt[i];
    const int ce = cnt[e];
    if (mt * 128 >= ce) return;

    __shared__ __bf16 lA[2][8192];   // 2 x 16 KB
    __shared__ __bf16 lB[2][8192];

    const int tid  = threadIdx.x;
    const int lane = tid & 63;
    const int wid  = tid >> 6;
    const int quad = lane >> 4;
    const int l16  = lane & 15;
    const int wm   = wid & 1;
    const int wn   = wid >> 1;

    // staging: group g = wid*4+j covers rows g*8..g*8+7 (R5-verified pattern)
    const int lrow = lane >> 3;              // row within 8-row group
    const int cch  = (lane & 7) ^ lrow;      // global 16B-chunk within row
    const __bf16* aros[4]; const __bf16* bros[4];
    int ldsoff[4];
#pragma unroll
    for (int j = 0; j < 4; j++) {
        const int g   = wid * 4 + j;
        const int row = g * 8 + lrow;                 // tile row 0..127
        int gr = off_e + mt * 128 + row;
        gr = gr < 2 * N_TOK - 1 ? gr : 2 * N_TOK - 1;
        const int tok = row_token[gr] & (N_TOK - 1);
        aros[j] = xb  + (size_t)tok * DIM + cch * 8;
        bros[j] = w1t + ((size_t)e * HID + n0 + row) * DIM + cch * 8;
        ldsoff[j] = g * 1024;
    }

    f32x4 acc[4][4] = {};

    // prologue: DMA for kk=0 into buffer 0
#pragma unroll
    for (int j = 0; j < 4; j++) gload16(aros[j], (char*)lA[0] + ldsoff[j]);
#pragma unroll
    for (int j = 0; j < 4; j++) gload16(bros[j], (char*)lB[0] + ldsoff[j]);

    for (int kk = 0; kk < DIM; kk += 64) {
        const int b = (kk >> 6) & 1;
        __syncthreads();   // drains DMA(kk) (issued last iter) + protects WAR on buf b^1
        if (kk + 64 < DIM) {
            const int nb = b ^ 1;
#pragma unroll
            for (int j = 0; j < 4; j++) gload16(aros[j] + kk + 64, (char*)lA[nb] + ldsoff[j]);
#pragma unroll
            for (int j = 0; j < 4; j++) gload16(bros[j] + kk + 64, (char*)lB[nb] + ldsoff[j]);
        }
#pragma unroll
        for (int hh = 0; hh < 2; hh++) {
            const int sw = (((hh * 4 + quad) ^ (l16 & 7)) << 4);
            bf16x8 af[4], bfr[4];
#pragma unroll
            for (int mi = 0; mi < 4; mi++)
                af[mi] = *(const bf16x8*)((const char*)lA[b] + (wm * 64 + mi * 16 + l16) * 128 + sw);
#pragma unroll
            for (int ni = 0; ni < 4; ni++)
                bfr[ni] = *(const bf16x8*)((const char*)lB[b] + (wn * 64 + ni * 16 + l16) * 128 + sw);
#pragma unroll
            for (int mi = 0; mi < 4; mi++)
#pragma unroll
                for (int ni = 0; ni < 4; ni++)
                    acc[mi][ni] = __builtin_amdgcn_mfma_f32_16x16x32_bf16(af[mi], bfr[ni], acc[mi][ni], 0, 0, 0);
        }
    }

#pragma unroll
    for (int ni = 0; ni < 4; ni++) {
        const int col = n0 + wn * 64 + ni * 16 + l16;
        const float bias = b1[e * HID + col];
#pragma unroll
        for (int mi = 0; mi < 4; mi++) {
#pragma unroll
            for (int r = 0; r < 4; r++) {
                const int lr = wm * 64 + mi * 16 + quad * 4 + r;
                const int gm = mt * 128 + lr;
                if (gm < ce) {
                    float v = acc[mi][ni][r] + bias;
                    v = v > 0.f ? v : 0.f;
                    h[(size_t)(off_e + gm) * HID + col] = (__bf16)v;
                }
            }
        }
    }
}

// ---------------------------------------------------------------------------
// Grouped GEMM2: y[r] = h[r] @ W2t[e] + b2[e], fp32 out. Same dbuf structure.
// ---------------------------------------------------------------------------
__global__ __launch_bounds__(256, 2) void gemm2_kernel(
    const __bf16* __restrict__ h, const __bf16* __restrict__ w2t,
    const float* __restrict__ b2, const int* __restrict__ cnt,
    float* __restrict__ y) {
    const int lin = blockIdx.x;
    const int e   = lin & 7;
    const int t   = lin >> 3;
    const int n0  = (t & 7) * 128;
    const int mt  = t >> 3;
    int off_e = 0;
    for (int i = 0; i < e; i++) off_e += cnt[i];
    const int ce = cnt[e];
    if (mt * 128 >= ce) return;

    __shared__ __bf16 lA[2][8192];
    __shared__ __bf16 lB[2][8192];

    const int tid  = threadIdx.x;
    const int lane = tid & 63;
    const int wid  = tid >> 6;
    const int quad = lane >> 4;
    const int l16  = lane & 15;
    const int wm   = wid & 1;
    const int wn   = wid >> 1;

    const int lrow = lane >> 3;
    const int cch  = (lane & 7) ^ lrow;
    const __bf16* aros[4]; const __bf16* bros[4];
    int ldsoff[4];
#pragma unroll
    for (int j = 0; j < 4; j++) {
        const int g   = wid * 4 + j;
        const int row = g * 8 + lrow;
        int gr = off_e + mt * 128 + row;
        gr = gr < 2 * N_TOK - 1 ? gr : 2 * N_TOK - 1;   // clamp inside h buffer
        aros[j] = h   + (size_t)gr * HID + cch * 8;
        bros[j] = w2t + ((size_t)e * DIM + n0 + row) * HID + cch * 8;
        ldsoff[j] = g * 1024;
    }

    f32x4 acc[4][4] = {};

#pragma unroll
    for (int j = 0; j < 4; j++) gload16(aros[j], (char*)lA[0] + ldsoff[j]);
#pragma unroll
    for (int j = 0; j < 4; j++) gload16(bros[j], (char*)lB[0] + ldsoff[j]);

    for (int kk = 0; kk < HID; kk += 64) {
        const int b = (kk >> 6) & 1;
        __syncthreads();
        if (kk + 64 < HID) {
            const int nb = b ^ 1;
#pragma unroll
            for (int j = 0; j < 4; j++) gload16(aros[j] + kk + 64, (char*)lA[nb] + ldsoff[j]);
#pragma unroll
            for (int j = 0; j < 4; j++) gload16(bros[j] + kk + 64, (char*)lB[nb] + ldsoff[j]);
        }
#pragma unroll
        for (int hh = 0; hh < 2; hh++) {
            const int sw = (((hh * 4 + quad) ^ (l16 & 7)) << 4);
            bf16x8 af[4], bfr[4];
#pragma unroll
            for (int mi = 0; mi < 4; mi++)
                af[mi] = *(const bf16x8*)((const char*)lA[b] + (wm * 64 + mi * 16 + l16) * 128 + sw);
#pragma unroll
            for (int ni = 0; ni < 4; ni++)
                bfr[ni] = *(const bf16x8*)((const char*)lB[b] + (wn * 64 + ni * 16 + l16) * 128 + sw);
#pragma unroll
            for (int mi = 0; mi < 4; mi++)
#pragma unroll
                for (int ni = 0; ni < 4; ni++)
                    acc[mi][ni] = __builtin_amdgcn_mfma_f32_16x16x32_bf16(af[mi], bfr[ni], acc[mi][ni], 0, 0, 0);
        }
    }

#pragma unroll
    for (int mi = 0; mi < 4; mi++) {
#pragma unroll
        for (int r = 0; r < 4; r++) {
            const int lr = wm * 64 + mi * 16 + quad * 4 + r;
            const int gm = mt * 128 + lr;
            if (gm < ce) {
#pragma unroll
                for (int ni = 0; ni < 4; ni++) {
                    const int col = n0 + wn * 64 + ni * 16 + l16;
                    y[(size_t)(off_e + gm) * DIM + col] = acc[mi][ni][r] + b2[e * DIM + col];
                }
            }
        }
    }
}

// out[n] = g0*y[r0] + g1*y[r1] — coalesced, one block per token row.
__global__ void combine_kernel(const float* __restrict__ y, const int* __restrict__ tok_row,
                               const float* __restrict__ top_gate, float* __restrict__ out) {
    const int n = blockIdx.x;
    const int d = threadIdx.x * 4;
    const int r0 = tok_row[n * 2], r1 = tok_row[n * 2 + 1];
    const float g0 = top_gate[n * 2], g1 = top_gate[n * 2 + 1];
    float4 a = *(const float4*)&y[(size_t)r0 * DIM + d];
    float4 b = *(const float4*)&y[(size_t)r1 * DIM + d];
    float4 o = { g0 * a.x + g1 * b.x, g0 * a.y + g1 * b.y,
                 g0 * a.z + g1 * b.z, g0 * a.w + g1 * b.w };
    *(float4*)&out[(size_t)n * DIM + d] = o;
}

// ---------------------------------------------------------------------------
extern "C" void kernel_launch(void* const* d_in, const int* in_sizes, int n_in,
                              void* d_out, int out_size, void* d_ws, size_t ws_size,
                              hipStream_t stream) {
    const float* x  = (const float*)d_in[0];
    const float* gW = (const float*)d_in[1];
    const float* gb = (const float*)d_in[2];
    const float* W1 = (const float*)d_in[3];
    const float* b1 = (const float*)d_in[4];
    const float* W2 = (const float*)d_in[5];
    const float* b2 = (const float*)d_in[6];
    float* out = (float*)d_out;

    char* ws = (char*)d_ws;
    // ws layout:
    //   [0, 8 MiB)    xb  : x bf16 [N][D]
    //   [8, 40 MiB)   w1t : W1^T bf16 [E][H][D]   (dead after gemm1)
    //   [8, 40 MiB)   y   : fp32 [2N][D]          (overlays w1t)
    //   [40, 72 MiB)  w2t : W2^T bf16 [E][D][H]
    //   [72, 104 MiB) h   : bf16 [2N][H]
    //   [104 MiB..)   routing metadata
    __bf16* xb   = (__bf16*)(ws);
    __bf16* w1t  = (__bf16*)(ws + ((size_t)8  << 20));
    float*  ybuf = (float*) (ws + ((size_t)8  << 20));
    __bf16* w2t  = (__bf16*)(ws + ((size_t)40 << 20));
    __bf16* hbuf = (__bf16*)(ws + ((size_t)72 << 20));
    char* tail   = ws + ((size_t)104 << 20);
    int*   row_token = (int*)(tail);
    int*   tok_row   = (int*)(tail + 32768);
    int*   top_idx   = (int*)(tail + 65536);
    float* top_gate  = (float*)(tail + 98304);
    int*   cnt       = (int*)(tail + 131072);
    int*   run       = cnt + 32;

    hipMemsetAsync(cnt, 0, 256, stream);

    gate_kernel<<<N_TOK / 4, 256, 0, stream>>>(x, gW, gb, top_idx, top_gate, xb);
    count_kernel<<<N_TOK / 256, 256, 0, stream>>>(top_idx, cnt);
    build_kernel<<<N_TOK / 256, 256, 0, stream>>>(top_idx, cnt, run, row_token, tok_row);
    transpose_cvt_all<<<32768, 256, 0, stream>>>(W1, W2, w1t, w2t);
    // XCD-aware packed grids: lin = e + 8*t, n0t fast / mt slow
    gemm1_kernel<<<NE * 32 * (HID / 128), 256, 0, stream>>>(xb, w1t, b1, cnt, row_token, hbuf);
    gemm2_kernel<<<NE * 32 * (DIM / 128), 256, 0, stream>>>(hbuf, w2t, b2, cnt, ybuf);
    combine_kernel<<<N_TOK, 256, 0, stream>>>(ybuf, tok_row, top_gate, out);
}

// Round 9
// 313.000 us; speedup vs baseline: 1.1524x; 1.1524x over previous
//
#include <hip/hip_runtime.h>
#include <hip/hip_bf16.h>
#include <cstdint>

// Problem constants: N=4096 tokens, D=1024, H=2048, E=8, TOP_K=2
#define N_TOK 4096
#define DIM   1024
#define HID   2048
#define NE    8

typedef __bf16 bf16x8 __attribute__((ext_vector_type(8)));
typedef __bf16 bf16x4 __attribute__((ext_vector_type(4)));
typedef float  f32x4  __attribute__((ext_vector_type(4)));

// Async global->LDS DMA, 16B/lane. LDS dest = wave-uniform base + lane*16.
__device__ __forceinline__ void gload16(const void* g, void* l) {
    __builtin_amdgcn_global_load_lds(
        (const __attribute__((address_space(1))) void*)g,
        (__attribute__((address_space(3))) void*)l, 16, 0, 0);
}

// ---------------------------------------------------------------------------
// Weight transpose + fp32->bf16, 64x64 tiles, both weights in one launch.
// lin<4096: W1 [D][H]->[H][D]; else W2 [H][D]->[D][H].
// Loads: 256B/row segments; stores: 128B/row segments; LDS 2-way only.
// ---------------------------------------------------------------------------
__global__ __launch_bounds__(256) void transpose_cvt_all(
    const float* __restrict__ W1, const float* __restrict__ W2,
    __bf16* __restrict__ w1t, __bf16* __restrict__ w2t) {
    int lin = blockIdx.x;
    const float* src; __bf16* dst; int R, C, rx, cy;
    if (lin < 4096) {
        const int e = lin >> 9, rem = lin & 511;
        rx = rem >> 5; cy = rem & 31;           // D/64=16, H/64=32
        R = DIM; C = HID;
        src = W1 + (size_t)e * DIM * HID; dst = w1t + (size_t)e * DIM * HID;
    } else {
        lin -= 4096;
        const int e = lin >> 9, rem = lin & 511;
        rx = rem >> 4; cy = rem & 15;           // H/64=32, D/64=16
        R = HID; C = DIM;
        src = W2 + (size_t)e * DIM * HID; dst = w2t + (size_t)e * DIM * HID;
    }
    __shared__ float t[64][65];
    const int r0 = rx * 64, c0 = cy * 64;
    const int tid = threadIdx.x;
    {   // load 64x64 fp32: thread -> row tid>>2, cols (tid&3)*16 + 4j
        const int tr = tid >> 2;
        const int tc = (tid & 3) * 16;
        const float* s = &src[(size_t)(r0 + tr) * C + c0 + tc];
#pragma unroll
        for (int j = 0; j < 4; j++) {
            float4 v = *(const float4*)(s + 4 * j);
            t[tr][tc + 4 * j + 0] = v.x; t[tr][tc + 4 * j + 1] = v.y;
            t[tr][tc + 4 * j + 2] = v.z; t[tr][tc + 4 * j + 3] = v.w;
        }
    }
    __syncthreads();
    {   // store: dst row c0+cidx gets elements r0+seg*16..+15 = t[seg*16+i][cidx]
        const int cidx = tid >> 2;
        const int seg  = tid & 3;
        bf16x8 o0, o1;
#pragma unroll
        for (int i = 0; i < 8; i++) o0[i] = (__bf16)t[seg * 16 + i][cidx];
#pragma unroll
        for (int i = 0; i < 8; i++) o1[i] = (__bf16)t[seg * 16 + 8 + i][cidx];
        __bf16* d = &dst[(size_t)(c0 + cidx) * R + r0 + seg * 16];
        *(bf16x8*)(d)     = o0;
        *(bf16x8*)(d + 8) = o1;
    }
}

// ---------------------------------------------------------------------------
// Gating + x->bf16 conversion fused. One wave per token. No atomics.
// ---------------------------------------------------------------------------
__global__ void gate_kernel(const float* __restrict__ x, const float* __restrict__ gW,
                            const float* __restrict__ gb, int* __restrict__ top_idx,
                            float* __restrict__ top_gate, __bf16* __restrict__ xb) {
    const int tokn = blockIdx.x * 4 + (threadIdx.x >> 6);
    const int lane = threadIdx.x & 63;
    const float4* xr = (const float4*)(x + (size_t)tokn * DIM);
    __bf16* xbr = xb + (size_t)tokn * DIM;
    float acc[NE] = {};
#pragma unroll
    for (int i = 0; i < 4; i++) {
        const int v4 = i * 64 + lane;            // float4 index 0..255
        const float4 xv = xr[v4];
        bf16x4 xc = { (__bf16)xv.x, (__bf16)xv.y, (__bf16)xv.z, (__bf16)xv.w };
        *(bf16x4*)&xbr[v4 * 4] = xc;
        const float* wb = &gW[v4 * 4 * NE];      // 4 rows x 8 experts
        const float xs[4] = { xv.x, xv.y, xv.z, xv.w };
#pragma unroll
        for (int j = 0; j < 4; j++) {
            const float4 wa = *(const float4*)&wb[j * NE];
            const float4 wc = *(const float4*)&wb[j * NE + 4];
            acc[0] += xs[j] * wa.x; acc[1] += xs[j] * wa.y;
            acc[2] += xs[j] * wa.z; acc[3] += xs[j] * wa.w;
            acc[4] += xs[j] * wc.x; acc[5] += xs[j] * wc.y;
            acc[6] += xs[j] * wc.z; acc[7] += xs[j] * wc.w;
        }
    }
#pragma unroll
    for (int e = 0; e < NE; e++)
#pragma unroll
        for (int s = 32; s > 0; s >>= 1)
            acc[e] += __shfl_down(acc[e], s, 64);
    if (lane == 0) {
        float lg[NE], p[NE];
        float mx = -1e30f;
#pragma unroll
        for (int e = 0; e < NE; e++) { lg[e] = acc[e] + gb[e]; mx = fmaxf(mx, lg[e]); }
        float s = 0.f;
#pragma unroll
        for (int e = 0; e < NE; e++) { p[e] = __expf(lg[e] - mx); s += p[e]; }
        const float inv = 1.f / s;
#pragma unroll
        for (int e = 0; e < NE; e++) p[e] *= inv;
        int i0 = 0; float p0 = p[0];
#pragma unroll
        for (int e = 1; e < NE; e++) if (p[e] > p0) { p0 = p[e]; i0 = e; }
        int i1 = -1; float p1 = -1.f;
#pragma unroll
        for (int e = 0; e < NE; e++) if (e != i0 && p[e] > p1) { p1 = p[e]; i1 = e; }
        top_idx[tokn * 2] = i0;  top_idx[tokn * 2 + 1] = i1;
        top_gate[tokn * 2] = p0; top_gate[tokn * 2 + 1] = p1;
    }
}

// LDS histogram -> 8 global atomics per block (16 blocks => 128 total).
__global__ void count_kernel(const int* __restrict__ top_idx, int* __restrict__ cnt) {
    __shared__ int hist[NE];
    if (threadIdx.x < NE) hist[threadIdx.x] = 0;
    __syncthreads();
    const int n = blockIdx.x * 256 + threadIdx.x;
    atomicAdd(&hist[top_idx[n * 2]], 1);
    atomicAdd(&hist[top_idx[n * 2 + 1]], 1);
    __syncthreads();
    if (threadIdx.x < NE) atomicAdd(&cnt[threadIdx.x], hist[threadIdx.x]);
}

// Row assignment: inline 8-wide prefix scan + LDS ranks + 8 global atomics/block.
__global__ void build_kernel(const int* __restrict__ top_idx, const int* __restrict__ cnt,
                             int* __restrict__ run, int* __restrict__ row_token,
                             int* __restrict__ tok_row) {
    __shared__ int soffs[NE];
    __shared__ int lrun[NE];
    __shared__ int base[NE];
    if (threadIdx.x == 0) {
        int s = 0;
        for (int e = 0; e < NE; e++) { soffs[e] = s; s += cnt[e]; }
    }
    if (threadIdx.x < NE) lrun[threadIdx.x] = 0;
    __syncthreads();
    const int n = blockIdx.x * 256 + threadIdx.x;
    const int e0 = top_idx[n * 2], e1 = top_idx[n * 2 + 1];
    const int p0 = atomicAdd(&lrun[e0], 1);
    const int p1 = atomicAdd(&lrun[e1], 1);
    __syncthreads();
    if (threadIdx.x < NE) base[threadIdx.x] = atomicAdd(&run[threadIdx.x], lrun[threadIdx.x]);
    __syncthreads();
    const int r0 = soffs[e0] + base[e0] + p0;
    const int r1 = soffs[e1] + base[e1] + p1;
    row_token[r0] = n; tok_row[n * 2] = r0;
    row_token[r1] = n; tok_row[n * 2 + 1] = r1;
}

// ---------------------------------------------------------------------------
// Grouped GEMM1 (R5-verified structure): h[r] = relu(x[tok(r)] @ W1t[e] + b1[e]).
// 128x128 tile, BK=64, global_load_lds(16B), XOR-swizzled LDS (conflict-free).
// XCD-aware 1-D grid: lin = e + 8*(n0t*32 + mt), mt fast => B-tile sharers
// temporally adjacent on one XCD's L2; xcd ~= e.
// ---------------------------------------------------------------------------
__global__ __launch_bounds__(256, 2) void gemm1_kernel(
    const __bf16* __restrict__ xb, const __bf16* __restrict__ w1t,
    const float* __restrict__ b1, const int* __restrict__ cnt,
    const int* __restrict__ row_token, __bf16* __restrict__ h) {
    const int lin = blockIdx.x;
    const int e   = lin & 7;
    const int t   = lin >> 3;
    const int mt  = t & 31;
    const int n0  = (t >> 5) * 128;
    int off_e = 0;
    for (int i = 0; i < e; i++) off_e += cnt[i];
    const int ce = cnt[e];
    if (mt * 128 >= ce) return;

    __shared__ __bf16 lA[8192];   // 128 rows x 64 cols = 16KB, swizzled
    __shared__ __bf16 lB[8192];

    const int tid  = threadIdx.x;
    const int lane = tid & 63;
    const int wid  = tid >> 6;
    const int quad = lane >> 4;
    const int l16  = lane & 15;
    const int wm   = wid & 1;
    const int wn   = wid >> 1;

    const int lrow = lane >> 3;              // row within 8-row group
    const int cch  = (lane & 7) ^ lrow;      // global 16B-chunk within row
    const __bf16* aros[4]; const __bf16* bros[4];
    char* ldsA[4]; char* ldsB[4];
#pragma unroll
    for (int j = 0; j < 4; j++) {
        const int row = (wid * 4 + j) * 8 + lrow;     // tile row 0..127
        int gr = off_e + mt * 128 + row;
        gr = gr < 2 * N_TOK - 1 ? gr : 2 * N_TOK - 1;
        const int tok = row_token[gr] & (N_TOK - 1);
        aros[j] = xb  + (size_t)tok * DIM + cch * 8;
        bros[j] = w1t + ((size_t)e * HID + n0 + row) * DIM + cch * 8;
        ldsA[j] = (char*)lA + (wid * 4 + j) * 1024;
        ldsB[j] = (char*)lB + (wid * 4 + j) * 1024;
    }

    f32x4 acc[4][4] = {};

    for (int kk = 0; kk < DIM; kk += 64) {
#pragma unroll
        for (int j = 0; j < 4; j++) gload16(aros[j] + kk, ldsA[j]);
#pragma unroll
        for (int j = 0; j < 4; j++) gload16(bros[j] + kk, ldsB[j]);
        __syncthreads();
#pragma unroll
        for (int hh = 0; hh < 2; hh++) {
            const int sw = (((hh * 4 + quad) ^ (l16 & 7)) << 4);
            bf16x8 af[4], bfr[4];
#pragma unroll
            for (int mi = 0; mi < 4; mi++)
                af[mi] = *(const bf16x8*)((const char*)lA + (wm * 64 + mi * 16 + l16) * 128 + sw);
#pragma unroll
            for (int ni = 0; ni < 4; ni++)
                bfr[ni] = *(const bf16x8*)((const char*)lB + (wn * 64 + ni * 16 + l16) * 128 + sw);
#pragma unroll
            for (int mi = 0; mi < 4; mi++)
#pragma unroll
                for (int ni = 0; ni < 4; ni++)
                    acc[mi][ni] = __builtin_amdgcn_mfma_f32_16x16x32_bf16(af[mi], bfr[ni], acc[mi][ni], 0, 0, 0);
        }
        __syncthreads();
    }

#pragma unroll
    for (int ni = 0; ni < 4; ni++) {
        const int col = n0 + wn * 64 + ni * 16 + l16;
        const float bias = b1[e * HID + col];
#pragma unroll
        for (int mi = 0; mi < 4; mi++) {
#pragma unroll
            for (int r = 0; r < 4; r++) {
                const int lr = wm * 64 + mi * 16 + quad * 4 + r;
                const int gm = mt * 128 + lr;
                if (gm < ce) {
                    float v = acc[mi][ni][r] + bias;
                    v = v > 0.f ? v : 0.f;
                    h[(size_t)(off_e + gm) * HID + col] = (__bf16)v;
                }
            }
        }
    }
}

// ---------------------------------------------------------------------------
// Grouped GEMM2 (R5 structure): y[r] = h[r] @ W2t[e] + b2[e], bf16 out.
// ---------------------------------------------------------------------------
__global__ __launch_bounds__(256, 2) void gemm2_kernel(
    const __bf16* __restrict__ h, const __bf16* __restrict__ w2t,
    const float* __restrict__ b2, const int* __restrict__ cnt,
    __bf16* __restrict__ y) {
    const int lin = blockIdx.x;
    const int e   = lin & 7;
    const int t   = lin >> 3;
    const int mt  = t & 31;
    const int n0  = (t >> 5) * 128;
    int off_e = 0;
    for (int i = 0; i < e; i++) off_e += cnt[i];
    const int ce = cnt[e];
    if (mt * 128 >= ce) return;

    __shared__ __bf16 lA[8192];
    __shared__ __bf16 lB[8192];

    const int tid  = threadIdx.x;
    const int lane = tid & 63;
    const int wid  = tid >> 6;
    const int quad = lane >> 4;
    const int l16  = lane & 15;
    const int wm   = wid & 1;
    const int wn   = wid >> 1;

    const int lrow = lane >> 3;
    const int cch  = (lane & 7) ^ lrow;
    const __bf16* aros[4]; const __bf16* bros[4];
    char* ldsA[4]; char* ldsB[4];
#pragma unroll
    for (int j = 0; j < 4; j++) {
        const int row = (wid * 4 + j) * 8 + lrow;
        int gr = off_e + mt * 128 + row;
        gr = gr < 2 * N_TOK - 1 ? gr : 2 * N_TOK - 1;   // clamp inside h buffer
        aros[j] = h   + (size_t)gr * HID + cch * 8;
        bros[j] = w2t + ((size_t)e * DIM + n0 + row) * HID + cch * 8;
        ldsA[j] = (char*)lA + (wid * 4 + j) * 1024;
        ldsB[j] = (char*)lB + (wid * 4 + j) * 1024;
    }

    f32x4 acc[4][4] = {};

    for (int kk = 0; kk < HID; kk += 64) {
#pragma unroll
        for (int j = 0; j < 4; j++) gload16(aros[j] + kk, ldsA[j]);
#pragma unroll
        for (int j = 0; j < 4; j++) gload16(bros[j] + kk, ldsB[j]);
        __syncthreads();
#pragma unroll
        for (int hh = 0; hh < 2; hh++) {
            const int sw = (((hh * 4 + quad) ^ (l16 & 7)) << 4);
            bf16x8 af[4], bfr[4];
#pragma unroll
            for (int mi = 0; mi < 4; mi++)
                af[mi] = *(const bf16x8*)((const char*)lA + (wm * 64 + mi * 16 + l16) * 128 + sw);
#pragma unroll
            for (int ni = 0; ni < 4; ni++)
                bfr[ni] = *(const bf16x8*)((const char*)lB + (wn * 64 + ni * 16 + l16) * 128 + sw);
#pragma unroll
            for (int mi = 0; mi < 4; mi++)
#pragma unroll
                for (int ni = 0; ni < 4; ni++)
                    acc[mi][ni] = __builtin_amdgcn_mfma_f32_16x16x32_bf16(af[mi], bfr[ni], acc[mi][ni], 0, 0, 0);
        }
        __syncthreads();
    }

#pragma unroll
    for (int mi = 0; mi < 4; mi++) {
#pragma unroll
        for (int r = 0; r < 4; r++) {
            const int lr = wm * 64 + mi * 16 + quad * 4 + r;
            const int gm = mt * 128 + lr;
            if (gm < ce) {
#pragma unroll
                for (int ni = 0; ni < 4; ni++) {
                    const int col = n0 + wn * 64 + ni * 16 + l16;
                    y[(size_t)(off_e + gm) * DIM + col] = (__bf16)(acc[mi][ni][r] + b2[e * DIM + col]);
                }
            }
        }
    }
}

// out[n] = g0*y[r0] + g1*y[r1] — coalesced, one block per token row. y is bf16.
__global__ void combine_kernel(const __bf16* __restrict__ y, const int* __restrict__ tok_row,
                               const float* __restrict__ top_gate, float* __restrict__ out) {
    const int n = blockIdx.x;
    const int d = threadIdx.x * 4;
    const int r0 = tok_row[n * 2], r1 = tok_row[n * 2 + 1];
    const float g0 = top_gate[n * 2], g1 = top_gate[n * 2 + 1];
    bf16x4 a = *(const bf16x4*)&y[(size_t)r0 * DIM + d];
    bf16x4 b = *(const bf16x4*)&y[(size_t)r1 * DIM + d];
    float4 o = { g0 * (float)a[0] + g1 * (float)b[0], g0 * (float)a[1] + g1 * (float)b[1],
                 g0 * (float)a[2] + g1 * (float)b[2], g0 * (float)a[3] + g1 * (float)b[3] };
    *(float4*)&out[(size_t)n * DIM + d] = o;
}

// ---------------------------------------------------------------------------
extern "C" void kernel_launch(void* const* d_in, const int* in_sizes, int n_in,
                              void* d_out, int out_size, void* d_ws, size_t ws_size,
                              hipStream_t stream) {
    const float* x  = (const float*)d_in[0];
    const float* gW = (const float*)d_in[1];
    const float* gb = (const float*)d_in[2];
    const float* W1 = (const float*)d_in[3];
    const float* b1 = (const float*)d_in[4];
    const float* W2 = (const float*)d_in[5];
    const float* b2 = (const float*)d_in[6];
    float* out = (float*)d_out;

    char* ws = (char*)d_ws;
    // ws layout:
    //   [0, 8 MiB)    xb  : x bf16 [N][D]
    //   [8, 40 MiB)   w1t : W1^T bf16 [E][H][D]   (dead after gemm1)
    //   [8, 40 MiB)   y   : bf16 [2N][D]          (overlays w1t)
    //   [40, 72 MiB)  w2t : W2^T bf16 [E][D][H]
    //   [72, 104 MiB) h   : bf16 [2N][H]
    //   [104 MiB..)   routing metadata
    __bf16* xb   = (__bf16*)(ws);
    __bf16* w1t  = (__bf16*)(ws + ((size_t)8  << 20));
    __bf16* ybuf = (__bf16*)(ws + ((size_t)8  << 20));
    __bf16* w2t  = (__bf16*)(ws + ((size_t)40 << 20));
    __bf16* hbuf = (__bf16*)(ws + ((size_t)72 << 20));
    char* tail   = ws + ((size_t)104 << 20);
    int*   row_token = (int*)(tail);
    int*   tok_row   = (int*)(tail + 32768);
    int*   top_idx   = (int*)(tail + 65536);
    float* top_gate  = (float*)(tail + 98304);
    int*   cnt       = (int*)(tail + 131072);
    int*   run       = cnt + 32;

    hipMemsetAsync(cnt, 0, 256, stream);

    gate_kernel<<<N_TOK / 4, 256, 0, stream>>>(x, gW, gb, top_idx, top_gate, xb);
    count_kernel<<<N_TOK / 256, 256, 0, stream>>>(top_idx, cnt);
    build_kernel<<<N_TOK / 256, 256, 0, stream>>>(top_idx, cnt, run, row_token, tok_row);
    transpose_cvt_all<<<8192, 256, 0, stream>>>(W1, W2, w1t, w2t);
    // XCD-aware 1-D grids: lin = e + 8*(n0t*32 + mt), mt fast
    gemm1_kernel<<<NE * 32 * (HID / 128), 256, 0, stream>>>(xb, w1t, b1, cnt, row_token, hbuf);
    gemm2_kernel<<<NE * 32 * (DIM / 128), 256, 0, stream>>>(hbuf, w2t, b2, cnt, ybuf);
    combine_kernel<<<N_TOK, 256, 0, stream>>>(ybuf, tok_row, top_gate, out);
}

// Round 10
// 304.802 us; speedup vs baseline: 1.1834x; 1.0269x over previous
//
#include <hip/hip_runtime.h>
#include <hip/hip_bf16.h>
#include <cstdint>

// Problem constants: N=4096 tokens, D=1024, H=2048, E=8, TOP_K=2
#define N_TOK 4096
#define DIM   1024
#define HID   2048
#define NE    8

typedef __bf16 bf16x8 __attribute__((ext_vector_type(8)));
typedef __bf16 bf16x4 __attribute__((ext_vector_type(4)));
typedef float  f32x4  __attribute__((ext_vector_type(4)));

// Async global->LDS DMA, 16B/lane. LDS dest = wave-uniform base + lane*16.
__device__ __forceinline__ void gload16(const void* g, void* l) {
    __builtin_amdgcn_global_load_lds(
        (const __attribute__((address_space(1))) void*)g,
        (__attribute__((address_space(3))) void*)l, 16, 0, 0);
}

// ---------------------------------------------------------------------------
// Über-kernel: gate + x->bf16 + both weight transposes + cnt/run zeroing,
// interleaved so gate blocks overlap the HBM-bound transpose.
// grid = 9216; group = lin/9, slot = lin%9. slot==8 -> gate block 'group'
// (1024 total); slot<8 -> transpose tile group*8+slot (8192 total).
// ---------------------------------------------------------------------------
__global__ __launch_bounds__(256) void uber_kernel(
    const float* __restrict__ x, const float* __restrict__ gW,
    const float* __restrict__ gb, const float* __restrict__ W1,
    const float* __restrict__ W2, int* __restrict__ top_idx,
    float* __restrict__ top_gate, __bf16* __restrict__ xb,
    __bf16* __restrict__ w1t, __bf16* __restrict__ w2t,
    int* __restrict__ cnt_run) {
    const int group = blockIdx.x / 9;
    const int slot  = blockIdx.x % 9;

    if (slot == 8) {
        // ----- gate path (block 'group' handles 4 tokens, 1 wave each) -----
        if (group == 0 && threadIdx.x < 64) cnt_run[threadIdx.x] = 0;  // cnt+run
        const int tokn = group * 4 + (threadIdx.x >> 6);
        const int lane = threadIdx.x & 63;
        const float4* xr = (const float4*)(x + (size_t)tokn * DIM);
        __bf16* xbr = xb + (size_t)tokn * DIM;
        float acc[NE] = {};
#pragma unroll
        for (int i = 0; i < 4; i++) {
            const int v4 = i * 64 + lane;            // float4 index 0..255
            const float4 xv = xr[v4];
            bf16x4 xc = { (__bf16)xv.x, (__bf16)xv.y, (__bf16)xv.z, (__bf16)xv.w };
            *(bf16x4*)&xbr[v4 * 4] = xc;
            const float* wb = &gW[v4 * 4 * NE];      // 4 rows x 8 experts
            const float xs[4] = { xv.x, xv.y, xv.z, xv.w };
#pragma unroll
            for (int j = 0; j < 4; j++) {
                const float4 wa = *(const float4*)&wb[j * NE];
                const float4 wc = *(const float4*)&wb[j * NE + 4];
                acc[0] += xs[j] * wa.x; acc[1] += xs[j] * wa.y;
                acc[2] += xs[j] * wa.z; acc[3] += xs[j] * wa.w;
                acc[4] += xs[j] * wc.x; acc[5] += xs[j] * wc.y;
                acc[6] += xs[j] * wc.z; acc[7] += xs[j] * wc.w;
            }
        }
#pragma unroll
        for (int e = 0; e < NE; e++)
#pragma unroll
            for (int s = 32; s > 0; s >>= 1)
                acc[e] += __shfl_down(acc[e], s, 64);
        if (lane == 0) {
            float lg[NE], p[NE];
            float mx = -1e30f;
#pragma unroll
            for (int e = 0; e < NE; e++) { lg[e] = acc[e] + gb[e]; mx = fmaxf(mx, lg[e]); }
            float s = 0.f;
#pragma unroll
            for (int e = 0; e < NE; e++) { p[e] = __expf(lg[e] - mx); s += p[e]; }
            const float inv = 1.f / s;
#pragma unroll
            for (int e = 0; e < NE; e++) p[e] *= inv;
            int i0 = 0; float p0 = p[0];
#pragma unroll
            for (int e = 1; e < NE; e++) if (p[e] > p0) { p0 = p[e]; i0 = e; }
            int i1 = -1; float p1 = -1.f;
#pragma unroll
            for (int e = 0; e < NE; e++) if (e != i0 && p[e] > p1) { p1 = p[e]; i1 = e; }
            top_idx[tokn * 2] = i0;  top_idx[tokn * 2 + 1] = i1;
            top_gate[tokn * 2] = p0; top_gate[tokn * 2 + 1] = p1;
        }
        return;
    }

    // ----- transpose path (64x64 tile, fp32->bf16) -----
    int t = group * 8 + slot;                  // 0..8191
    const float* src; __bf16* dst; int R, C, rx, cy;
    if (t < 4096) {
        const int e = t >> 9, rem = t & 511;
        rx = rem >> 5; cy = rem & 31;           // D/64=16, H/64=32
        R = DIM; C = HID;
        src = W1 + (size_t)e * DIM * HID; dst = w1t + (size_t)e * DIM * HID;
    } else {
        t -= 4096;
        const int e = t >> 9, rem = t & 511;
        rx = rem >> 4; cy = rem & 15;           // H/64=32, D/64=16
        R = HID; C = DIM;
        src = W2 + (size_t)e * DIM * HID; dst = w2t + (size_t)e * DIM * HID;
    }
    __shared__ float tl[64][65];
    const int r0 = rx * 64, c0 = cy * 64;
    const int tid = threadIdx.x;
    {   // load 64x64 fp32: thread -> row tid>>2, cols (tid&3)*16 + 4j
        const int tr = tid >> 2;
        const int tc = (tid & 3) * 16;
        const float* s = &src[(size_t)(r0 + tr) * C + c0 + tc];
#pragma unroll
        for (int j = 0; j < 4; j++) {
            float4 v = *(const float4*)(s + 4 * j);
            tl[tr][tc + 4 * j + 0] = v.x; tl[tr][tc + 4 * j + 1] = v.y;
            tl[tr][tc + 4 * j + 2] = v.z; tl[tr][tc + 4 * j + 3] = v.w;
        }
    }
    __syncthreads();
    {   // store: dst row c0+cidx gets elements r0+seg*16..+15
        const int cidx = tid >> 2;
        const int seg  = tid & 3;
        bf16x8 o0, o1;
#pragma unroll
        for (int i = 0; i < 8; i++) o0[i] = (__bf16)tl[seg * 16 + i][cidx];
#pragma unroll
        for (int i = 0; i < 8; i++) o1[i] = (__bf16)tl[seg * 16 + 8 + i][cidx];
        __bf16* d = &dst[(size_t)(c0 + cidx) * R + r0 + seg * 16];
        *(bf16x8*)(d)     = o0;
        *(bf16x8*)(d + 8) = o1;
    }
}

// LDS histogram -> 8 global atomics per block (16 blocks => 128 total).
__global__ void count_kernel(const int* __restrict__ top_idx, int* __restrict__ cnt) {
    __shared__ int hist[NE];
    if (threadIdx.x < NE) hist[threadIdx.x] = 0;
    __syncthreads();
    const int n = blockIdx.x * 256 + threadIdx.x;
    atomicAdd(&hist[top_idx[n * 2]], 1);
    atomicAdd(&hist[top_idx[n * 2 + 1]], 1);
    __syncthreads();
    if (threadIdx.x < NE) atomicAdd(&cnt[threadIdx.x], hist[threadIdx.x]);
}

// Row assignment: inline 8-wide prefix scan + LDS ranks + 8 global atomics/block.
__global__ void build_kernel(const int* __restrict__ top_idx, const int* __restrict__ cnt,
                             int* __restrict__ run, int* __restrict__ row_token,
                             int* __restrict__ tok_row) {
    __shared__ int soffs[NE];
    __shared__ int lrun[NE];
    __shared__ int base[NE];
    if (threadIdx.x == 0) {
        int s = 0;
        for (int e = 0; e < NE; e++) { soffs[e] = s; s += cnt[e]; }
    }
    if (threadIdx.x < NE) lrun[threadIdx.x] = 0;
    __syncthreads();
    const int n = blockIdx.x * 256 + threadIdx.x;
    const int e0 = top_idx[n * 2], e1 = top_idx[n * 2 + 1];
    const int p0 = atomicAdd(&lrun[e0], 1);
    const int p1 = atomicAdd(&lrun[e1], 1);
    __syncthreads();
    if (threadIdx.x < NE) base[threadIdx.x] = atomicAdd(&run[threadIdx.x], lrun[threadIdx.x]);
    __syncthreads();
    const int r0 = soffs[e0] + base[e0] + p0;
    const int r1 = soffs[e1] + base[e1] + p1;
    row_token[r0] = n; tok_row[n * 2] = r0;
    row_token[r1] = n; tok_row[n * 2 + 1] = r1;
}

// ---------------------------------------------------------------------------
// Grouped GEMM1 (R5-verified structure): h[r] = relu(x[tok(r)] @ W1t[e] + b1[e]).
// 128x128 tile, BK=64, global_load_lds(16B), XOR-swizzled LDS (conflict-free).
// XCD-aware 1-D grid: lin = e + 8*(n0t*32 + mt), mt fast; xcd ~= e.
// ---------------------------------------------------------------------------
__global__ __launch_bounds__(256, 2) void gemm1_kernel(
    const __bf16* __restrict__ xb, const __bf16* __restrict__ w1t,
    const float* __restrict__ b1, const int* __restrict__ cnt,
    const int* __restrict__ row_token, __bf16* __restrict__ h) {
    const int lin = blockIdx.x;
    const int e   = lin & 7;
    const int t   = lin >> 3;
    const int mt  = t & 31;
    const int n0  = (t >> 5) * 128;
    int off_e = 0;
    for (int i = 0; i < e; i++) off_e += cnt[i];
    const int ce = cnt[e];
    if (mt * 128 >= ce) return;

    __shared__ __bf16 lA[8192];   // 128 rows x 64 cols = 16KB, swizzled
    __shared__ __bf16 lB[8192];

    const int tid  = threadIdx.x;
    const int lane = tid & 63;
    const int wid  = tid >> 6;
    const int quad = lane >> 4;
    const int l16  = lane & 15;
    const int wm   = wid & 1;
    const int wn   = wid >> 1;

    const int lrow = lane >> 3;              // row within 8-row group
    const int cch  = (lane & 7) ^ lrow;      // global 16B-chunk within row
    const __bf16* aros[4]; const __bf16* bros[4];
    char* ldsA[4]; char* ldsB[4];
#pragma unroll
    for (int j = 0; j < 4; j++) {
        const int row = (wid * 4 + j) * 8 + lrow;     // tile row 0..127
        int gr = off_e + mt * 128 + row;
        gr = gr < 2 * N_TOK - 1 ? gr : 2 * N_TOK - 1;
        const int tok = row_token[gr] & (N_TOK - 1);
        aros[j] = xb  + (size_t)tok * DIM + cch * 8;
        bros[j] = w1t + ((size_t)e * HID + n0 + row) * DIM + cch * 8;
        ldsA[j] = (char*)lA + (wid * 4 + j) * 1024;
        ldsB[j] = (char*)lB + (wid * 4 + j) * 1024;
    }

    f32x4 acc[4][4] = {};

    for (int kk = 0; kk < DIM; kk += 64) {
#pragma unroll
        for (int j = 0; j < 4; j++) gload16(aros[j] + kk, ldsA[j]);
#pragma unroll
        for (int j = 0; j < 4; j++) gload16(bros[j] + kk, ldsB[j]);
        __syncthreads();
#pragma unroll
        for (int hh = 0; hh < 2; hh++) {
            const int sw = (((hh * 4 + quad) ^ (l16 & 7)) << 4);
            bf16x8 af[4], bfr[4];
#pragma unroll
            for (int mi = 0; mi < 4; mi++)
                af[mi] = *(const bf16x8*)((const char*)lA + (wm * 64 + mi * 16 + l16) * 128 + sw);
#pragma unroll
            for (int ni = 0; ni < 4; ni++)
                bfr[ni] = *(const bf16x8*)((const char*)lB + (wn * 64 + ni * 16 + l16) * 128 + sw);
#pragma unroll
            for (int mi = 0; mi < 4; mi++)
#pragma unroll
                for (int ni = 0; ni < 4; ni++)
                    acc[mi][ni] = __builtin_amdgcn_mfma_f32_16x16x32_bf16(af[mi], bfr[ni], acc[mi][ni], 0, 0, 0);
        }
        __syncthreads();
    }

#pragma unroll
    for (int ni = 0; ni < 4; ni++) {
        const int col = n0 + wn * 64 + ni * 16 + l16;
        const float bias = b1[e * HID + col];
#pragma unroll
        for (int mi = 0; mi < 4; mi++) {
#pragma unroll
            for (int r = 0; r < 4; r++) {
                const int lr = wm * 64 + mi * 16 + quad * 4 + r;
                const int gm = mt * 128 + lr;
                if (gm < ce) {
                    float v = acc[mi][ni][r] + bias;
                    v = v > 0.f ? v : 0.f;
                    h[(size_t)(off_e + gm) * HID + col] = (__bf16)v;
                }
            }
        }
    }
}

// ---------------------------------------------------------------------------
// Grouped GEMM2 (R5 structure): y[r] = h[r] @ W2t[e] + b2[e], bf16 out.
// ---------------------------------------------------------------------------
__global__ __launch_bounds__(256, 2) void gemm2_kernel(
    const __bf16* __restrict__ h, const __bf16* __restrict__ w2t,
    const float* __restrict__ b2, const int* __restrict__ cnt,
    __bf16* __restrict__ y) {
    const int lin = blockIdx.x;
    const int e   = lin & 7;
    const int t   = lin >> 3;
    const int mt  = t & 31;
    const int n0  = (t >> 5) * 128;
    int off_e = 0;
    for (int i = 0; i < e; i++) off_e += cnt[i];
    const int ce = cnt[e];
    if (mt * 128 >= ce) return;

    __shared__ __bf16 lA[8192];
    __shared__ __bf16 lB[8192];

    const int tid  = threadIdx.x;
    const int lane = tid & 63;
    const int wid  = tid >> 6;
    const int quad = lane >> 4;
    const int l16  = lane & 15;
    const int wm   = wid & 1;
    const int wn   = wid >> 1;

    const int lrow = lane >> 3;
    const int cch  = (lane & 7) ^ lrow;
    const __bf16* aros[4]; const __bf16* bros[4];
    char* ldsA[4]; char* ldsB[4];
#pragma unroll
    for (int j = 0; j < 4; j++) {
        const int row = (wid * 4 + j) * 8 + lrow;
        int gr = off_e + mt * 128 + row;
        gr = gr < 2 * N_TOK - 1 ? gr : 2 * N_TOK - 1;   // clamp inside h buffer
        aros[j] = h   + (size_t)gr * HID + cch * 8;
        bros[j] = w2t + ((size_t)e * DIM + n0 + row) * HID + cch * 8;
        ldsA[j] = (char*)lA + (wid * 4 + j) * 1024;
        ldsB[j] = (char*)lB + (wid * 4 + j) * 1024;
    }

    f32x4 acc[4][4] = {};

    for (int kk = 0; kk < HID; kk += 64) {
#pragma unroll
        for (int j = 0; j < 4; j++) gload16(aros[j] + kk, ldsA[j]);
#pragma unroll
        for (int j = 0; j < 4; j++) gload16(bros[j] + kk, ldsB[j]);
        __syncthreads();
#pragma unroll
        for (int hh = 0; hh < 2; hh++) {
            const int sw = (((hh * 4 + quad) ^ (l16 & 7)) << 4);
            bf16x8 af[4], bfr[4];
#pragma unroll
            for (int mi = 0; mi < 4; mi++)
                af[mi] = *(const bf16x8*)((const char*)lA + (wm * 64 + mi * 16 + l16) * 128 + sw);
#pragma unroll
            for (int ni = 0; ni < 4; ni++)
                bfr[ni] = *(const bf16x8*)((const char*)lB + (wn * 64 + ni * 16 + l16) * 128 + sw);
#pragma unroll
            for (int mi = 0; mi < 4; mi++)
#pragma unroll
                for (int ni = 0; ni < 4; ni++)
                    acc[mi][ni] = __builtin_amdgcn_mfma_f32_16x16x32_bf16(af[mi], bfr[ni], acc[mi][ni], 0, 0, 0);
        }
        __syncthreads();
    }

#pragma unroll
    for (int mi = 0; mi < 4; mi++) {
#pragma unroll
        for (int r = 0; r < 4; r++) {
            const int lr = wm * 64 + mi * 16 + quad * 4 + r;
            const int gm = mt * 128 + lr;
            if (gm < ce) {
#pragma unroll
                for (int ni = 0; ni < 4; ni++) {
                    const int col = n0 + wn * 64 + ni * 16 + l16;
                    y[(size_t)(off_e + gm) * DIM + col] = (__bf16)(acc[mi][ni][r] + b2[e * DIM + col]);
                }
            }
        }
    }
}

// out[n] = g0*y[r0] + g1*y[r1] — coalesced, one block per token row. y is bf16.
__global__ void combine_kernel(const __bf16* __restrict__ y, const int* __restrict__ tok_row,
                               const float* __restrict__ top_gate, float* __restrict__ out) {
    const int n = blockIdx.x;
    const int d = threadIdx.x * 4;
    const int r0 = tok_row[n * 2], r1 = tok_row[n * 2 + 1];
    const float g0 = top_gate[n * 2], g1 = top_gate[n * 2 + 1];
    bf16x4 a = *(const bf16x4*)&y[(size_t)r0 * DIM + d];
    bf16x4 b = *(const bf16x4*)&y[(size_t)r1 * DIM + d];
    float4 o = { g0 * (float)a[0] + g1 * (float)b[0], g0 * (float)a[1] + g1 * (float)b[1],
                 g0 * (float)a[2] + g1 * (float)b[2], g0 * (float)a[3] + g1 * (float)b[3] };
    *(float4*)&out[(size_t)n * DIM + d] = o;
}

// ---------------------------------------------------------------------------
extern "C" void kernel_launch(void* const* d_in, const int* in_sizes, int n_in,
                              void* d_out, int out_size, void* d_ws, size_t ws_size,
                              hipStream_t stream) {
    const float* x  = (const float*)d_in[0];
    const float* gW = (const float*)d_in[1];
    const float* gb = (const float*)d_in[2];
    const float* W1 = (const float*)d_in[3];
    const float* b1 = (const float*)d_in[4];
    const float* W2 = (const float*)d_in[5];
    const float* b2 = (const float*)d_in[6];
    float* out = (float*)d_out;

    char* ws = (char*)d_ws;
    // ws layout:
    //   [0, 8 MiB)    xb  : x bf16 [N][D]
    //   [8, 40 MiB)   w1t : W1^T bf16 [E][H][D]   (dead after gemm1)
    //   [8, 40 MiB)   y   : bf16 [2N][D]          (overlays w1t)
    //   [40, 72 MiB)  w2t : W2^T bf16 [E][D][H]
    //   [72, 104 MiB) h   : bf16 [2N][H]
    //   [104 MiB..)   routing metadata
    __bf16* xb   = (__bf16*)(ws);
    __bf16* w1t  = (__bf16*)(ws + ((size_t)8  << 20));
    __bf16* ybuf = (__bf16*)(ws + ((size_t)8  << 20));
    __bf16* w2t  = (__bf16*)(ws + ((size_t)40 << 20));
    __bf16* hbuf = (__bf16*)(ws + ((size_t)72 << 20));
    char* tail   = ws + ((size_t)104 << 20);
    int*   row_token = (int*)(tail);
    int*   tok_row   = (int*)(tail + 32768);
    int*   top_idx   = (int*)(tail + 65536);
    float* top_gate  = (float*)(tail + 98304);
    int*   cnt       = (int*)(tail + 131072);
    int*   run       = cnt + 32;

    // 1) fused gate + transpose + zeroing (9216 blocks, interleaved 8:1)
    uber_kernel<<<9216, 256, 0, stream>>>(x, gW, gb, W1, W2, top_idx, top_gate,
                                          xb, w1t, w2t, cnt);
    // 2) routing
    count_kernel<<<N_TOK / 256, 256, 0, stream>>>(top_idx, cnt);
    build_kernel<<<N_TOK / 256, 256, 0, stream>>>(top_idx, cnt, run, row_token, tok_row);
    // 3) grouped GEMMs (XCD-aware grids: lin = e + 8*(n0t*32 + mt), mt fast)
    gemm1_kernel<<<NE * 32 * (HID / 128), 256, 0, stream>>>(xb, w1t, b1, cnt, row_token, hbuf);
    gemm2_kernel<<<NE * 32 * (DIM / 128), 256, 0, stream>>>(hbuf, w2t, b2, cnt, ybuf);
    // 4) weighted combine
    combine_kernel<<<N_TOK, 256, 0, stream>>>(ybuf, tok_row, top_gate, out);
}